// Round 14
// baseline (33.907 us; speedup 1.0000x reference)
//
#include <hip/hip_runtime.h>

#define NC 4096
#define NK 1024
#define NSUB 64     // screening subset: first 64 coordinates of each row
#define THR 0.5f    // per-projection threshold. Exact bound for a true-hinge pair:
                    // |d(proj_S)| <= ||r_S|| * d_S <= 8 * 1e-4 = 8e-4  (d_S <= d).
                    // THR=0.5 is a 600x safety factor; expected survivors ~13
                    // (sigma(dProj) = sqrt(2*64) ~= 11.3, 4 independent screens).

static constexpr float MARGIN = 0.0001f;

// Four Walsh projections restricted to coords 0..63: r0=all+1, r1=sign(k&1),
// r2=sign(k&2), r3=sign(k&4); mutually orthogonal, ||r_S|| = 8 exactly.
// Reads 256 B per row (1 MB total, 16x less than full-row proj -- this round's
// single variable). One wave = 4 rows (16 lanes x float4 each); 256 blocks.
__global__ __launch_bounds__(256) void proj_kernel(const float* __restrict__ x,
                                                   float4* __restrict__ proj4,
                                                   float* __restrict__ out) {
    const int tid = threadIdx.x, lane = tid & 63, wid = tid >> 6;
    if (blockIdx.x == 0 && tid == 0) out[0] = 0.f;
    const int row = blockIdx.x * 16 + wid * 4 + (lane >> 4);
    const int t = lane & 15;                      // float4 index; coords 4t..4t+3
    const float4 v = reinterpret_cast<const float4*>(x + (size_t)row * NK)[t];
    const float e = v.x + v.y, f = v.z + v.w;
    const float g = v.x - v.y, h = v.z - v.w;
    float s0 = e + f;                             // ++++
    float s1 = g + h;                             // +-+-  (k&1)
    float s2 = e - f;                             // ++--  (k&2)
    float s3 = (t & 1) ? -(e + f) : (e + f);      // k&4 -> sign uniform per float4
    #pragma unroll
    for (int m = 1; m < 16; m <<= 1) {            // reduce across the row's 16 lanes
        s0 += __shfl_xor(s0, m); s1 += __shfl_xor(s1, m);
        s2 += __shfl_xor(s2, m); s3 += __shfl_xor(s3, m);
    }
    if (t == 0) proj4[row] = make_float4(s0, s1, s2, s3);
}

// Exact f32 hinge for one surviving pair (full 1024-coord distance).
__device__ inline float pair_hinge(const float* __restrict__ x, int i, int j) {
    const float4* xi = reinterpret_cast<const float4*>(x + (size_t)i * NK);
    const float4* xj = reinterpret_cast<const float4*>(x + (size_t)j * NK);
    float a0 = 0.f, a1 = 0.f, a2 = 0.f, a3 = 0.f;
    #pragma unroll 4
    for (int q = 0; q < NK / 4; q += 4) {
        const float4 p0 = xi[q + 0], q0 = xj[q + 0];
        const float4 p1 = xi[q + 1], q1 = xj[q + 1];
        const float4 p2 = xi[q + 2], q2 = xj[q + 2];
        const float4 p3 = xi[q + 3], q3 = xj[q + 3];
        float dx, dy, dz, dw;
        dx = p0.x - q0.x; dy = p0.y - q0.y; dz = p0.z - q0.z; dw = p0.w - q0.w;
        a0 += dx * dx + dy * dy + dz * dz + dw * dw;
        dx = p1.x - q1.x; dy = p1.y - q1.y; dz = p1.z - q1.z; dw = p1.w - q1.w;
        a1 += dx * dx + dy * dy + dz * dz + dw * dw;
        dx = p2.x - q2.x; dy = p2.y - q2.y; dz = p2.z - q2.z; dw = p2.w - q2.w;
        a2 += dx * dx + dy * dy + dz * dz + dw * dw;
        dx = p3.x - q3.x; dy = p3.y - q3.y; dz = p3.z - q3.z; dw = p3.w - q3.w;
        a3 += dx * dx + dy * dy + dz * dz + dw * dw;
    }
    const float d2 = (a0 + a1) + (a2 + a3);
    // hinge > 0 iff d2 < MARGIN^2; equivalent to max(0, MARGIN - sqrt(max(d2,0)))
    return (d2 < MARGIN * MARGIN) ? (MARGIN - sqrtf(fmaxf(d2, 0.f))) : 0.f;
}

// All-pairs 4-projection screen -- BYTE-IDENTICAL structure to round 13
// (registers-only, branch-free hot loop, mask record + post-loop walk).
// 512 blocks x 8 rows, 2 waves/SIMD.
__global__ __launch_bounds__(256) void screen_kernel(const float* __restrict__ x,
                                                     const float4* __restrict__ proj4,
                                                     float* __restrict__ out) {
    const int tid = threadIdx.x;
    float4 pj[16];
    #pragma unroll
    for (int jc = 0; jc < 16; ++jc) pj[jc] = proj4[jc * 256 + tid];
    const int i0 = blockIdx.x * 8;
    unsigned long long h0 = 0ull, h1 = 0ull;
    #pragma unroll
    for (int ii = 0; ii < 8; ++ii) {
        const int i = i0 + ii;
        const float4 pi = proj4[i];   // block-uniform load, L2-hit
        unsigned long long rowm = 0ull;
        #pragma unroll
        for (int jc = 0; jc < 16; ++jc) {
            const int j = jc * 256 + tid;
            const bool hit = (j > i) &
                (fabsf(pi.x - pj[jc].x) < THR) & (fabsf(pi.y - pj[jc].y) < THR) &
                (fabsf(pi.z - pj[jc].z) < THR) & (fabsf(pi.w - pj[jc].w) < THR);
            rowm |= (unsigned long long)hit << jc;
        }
        if (ii < 4) h0 |= rowm << (ii * 16);
        else        h1 |= rowm << ((ii - 4) * 16);
    }
    // Rare path: expected ~13 set bits device-wide.
    float local = 0.f;
    while (h0) {
        const int b = __ffsll(h0) - 1; h0 &= h0 - 1;
        local += pair_hinge(x, i0 + (b >> 4), (b & 15) * 256 + tid);
    }
    while (h1) {
        const int b = __ffsll(h1) - 1; h1 &= h1 - 1;
        local += pair_hinge(x, i0 + 4 + (b >> 4), (b & 15) * 256 + tid);
    }
    #pragma unroll
    for (int off = 32; off > 0; off >>= 1) local += __shfl_down(local, off);
    if ((tid & 63) == 0 && local != 0.f) atomicAdd(out, local);
}

extern "C" void kernel_launch(void* const* d_in, const int* in_sizes, int n_in,
                              void* d_out, int out_size, void* d_ws, size_t ws_size,
                              hipStream_t stream) {
    const float* x = (const float*)d_in[0];
    float* out = (float*)d_out;
    float4* proj4 = (float4*)d_ws;   // 64 KB

    proj_kernel<<<256, 256, 0, stream>>>(x, proj4, out);
    screen_kernel<<<512, 256, 0, stream>>>(x, proj4, out);
}

// Round 15
// 18.368 us; speedup vs baseline: 1.8460x; 1.8460x over previous
//
#include <hip/hip_runtime.h>

#define NC 4096
#define NK 1024
#define THR 0.5f    // per-projection threshold on 64-coord subset projections.
                    // Exact bound for a true-hinge pair: |d(proj_S)| <= ||r_S||*d_S
                    // <= 8*1e-4 (d_S <= d). THR=0.5 -> 600x safety margin;
                    // expected survivors ~13 device-wide (sigma ~= 11.3, 4 screens).

static constexpr float MARGIN = 0.0001f;

// Four Walsh projections restricted to coords 0..63: r0=all+1, r1=sign(k&1),
// r2=sign(k&2), r3=sign(k&4); mutually orthogonal, ||r_S|| = 8 exactly.
// Reads 256 B per row (1 MB total). One wave = 4 rows; 256 blocks.
__global__ __launch_bounds__(256) void proj_kernel(const float* __restrict__ x,
                                                   float4* __restrict__ proj4,
                                                   float* __restrict__ out) {
    const int tid = threadIdx.x, lane = tid & 63, wid = tid >> 6;
    if (blockIdx.x == 0 && tid == 0) out[0] = 0.f;
    const int row = blockIdx.x * 16 + wid * 4 + (lane >> 4);
    const int t = lane & 15;                      // float4 index; coords 4t..4t+3
    const float4 v = reinterpret_cast<const float4*>(x + (size_t)row * NK)[t];
    const float e = v.x + v.y, f = v.z + v.w;
    const float g = v.x - v.y, h = v.z - v.w;
    float s0 = e + f;                             // ++++
    float s1 = g + h;                             // +-+-  (k&1)
    float s2 = e - f;                             // ++--  (k&2)
    float s3 = (t & 1) ? -(e + f) : (e + f);      // k&4 -> sign uniform per float4
    #pragma unroll
    for (int m = 1; m < 16; m <<= 1) {            // reduce across the row's 16 lanes
        s0 += __shfl_xor(s0, m); s1 += __shfl_xor(s1, m);
        s2 += __shfl_xor(s2, m); s3 += __shfl_xor(s3, m);
    }
    if (t == 0) proj4[row] = make_float4(s0, s1, s2, s3);
}

// All-pairs 4-projection screen. Hot loop identical to round 14 (registers-
// only, branch-free, mask record). ROUND-15 CHANGE: the rare path is now
// WAVE-COOPERATIVE -- round 12-14 had each surviving pair processed by a
// single exec-masked lane as a ~512-load serial chain (~6 us/pair, the real
// cost of the 28 us screen). Now: ballot the owners, broadcast their masks,
// and all 64 lanes compute each survivor's exact distance with coalesced
// loads + shfl reduce (~0.3 us/pair).
__global__ __launch_bounds__(256) void screen_kernel(const float* __restrict__ x,
                                                     const float4* __restrict__ proj4,
                                                     float* __restrict__ out) {
    const int tid = threadIdx.x, lane = tid & 63;
    float4 pj[16];
    #pragma unroll
    for (int jc = 0; jc < 16; ++jc) pj[jc] = proj4[jc * 256 + tid];
    const int i0 = blockIdx.x * 8;
    unsigned long long h0 = 0ull, h1 = 0ull;
    #pragma unroll
    for (int ii = 0; ii < 8; ++ii) {
        const int i = i0 + ii;
        const float4 pi = proj4[i];   // block-uniform load, L2-hit
        unsigned long long rowm = 0ull;
        #pragma unroll
        for (int jc = 0; jc < 16; ++jc) {
            const int j = jc * 256 + tid;
            const bool hit = (j > i) &
                (fabsf(pi.x - pj[jc].x) < THR) & (fabsf(pi.y - pj[jc].y) < THR) &
                (fabsf(pi.z - pj[jc].z) < THR) & (fabsf(pi.w - pj[jc].w) < THR);
            rowm |= (unsigned long long)hit << jc;
        }
        if (ii < 4) h0 |= rowm << (ii * 16);
        else        h1 |= rowm << ((ii - 4) * 16);
    }

    // Wave-cooperative rare path (~13 pairs device-wide expected).
    float local = 0.f;
    unsigned long long ball = __ballot((h0 | h1) != 0ull);   // wave-uniform
    while (ball) {
        const int owner = __ffsll(ball) - 1; ball &= ball - 1;
        const unsigned long long m0 = __shfl(h0, owner);
        const unsigned long long m1 = __shfl(h1, owner);
        const int otid = __shfl(tid, owner);                 // owner's j-lane id
        #pragma unroll
        for (int half = 0; half < 2; ++half) {
            unsigned long long m = half ? m1 : m0;
            while (m) {
                const int b = __ffsll(m) - 1; m &= m - 1;
                const int i = i0 + half * 4 + (b >> 4);
                const int j = (b & 15) * 256 + otid;
                // all 64 lanes: coalesced full-row distance, 4 float4 each
                const float4* xi = reinterpret_cast<const float4*>(x + (size_t)i * NK);
                const float4* xj = reinterpret_cast<const float4*>(x + (size_t)j * NK);
                float d2 = 0.f;
                #pragma unroll
                for (int q = 0; q < 4; ++q) {
                    const float4 a = xi[q * 64 + lane];
                    const float4 c = xj[q * 64 + lane];
                    const float dx = a.x - c.x, dy = a.y - c.y;
                    const float dz = a.z - c.z, dw = a.w - c.w;
                    d2 += dx * dx + dy * dy + dz * dz + dw * dw;
                }
                #pragma unroll
                for (int off = 32; off > 0; off >>= 1) d2 += __shfl_down(d2, off);
                // hinge > 0 iff d2 < MARGIN^2 (== max(0, M - sqrt(max(d2,0))))
                if (lane == 0 && d2 < MARGIN * MARGIN)
                    local += MARGIN - sqrtf(fmaxf(d2, 0.f));
            }
        }
    }
    #pragma unroll
    for (int off = 32; off > 0; off >>= 1) local += __shfl_down(local, off);
    if (lane == 0 && local != 0.f) atomicAdd(out, local);
}

extern "C" void kernel_launch(void* const* d_in, const int* in_sizes, int n_in,
                              void* d_out, int out_size, void* d_ws, size_t ws_size,
                              hipStream_t stream) {
    const float* x = (const float*)d_in[0];
    float* out = (float*)d_out;
    float4* proj4 = (float4*)d_ws;   // 64 KB

    proj_kernel<<<256, 256, 0, stream>>>(x, proj4, out);
    screen_kernel<<<512, 256, 0, stream>>>(x, proj4, out);
}